// Round 1
// baseline (63444.684 us; speedup 1.0000x reference)
//
#include <hip/hip_runtime.h>

// NeuralODE: SIREN MLP (2->128->128->2, sin, w0=44) + RK4 3/8-rule, 100 steps.
// Round 1: fp32 baseline. One thread per particle; h1[128] in VGPRs; W2
// pre-transposed + w0-prescaled into d_ws so inner-loop reads are wave-uniform
// (scalar s_load path), feeding v_fma_f32 with an SGPR operand.

#define SIREN_W0 44.0f
#define WIDTH    128
#define NPART    262144
#define TSTEPS   101

// ws layout (floats): [0,16384) W2s[j][k] = w0*W2[k][j]
//                     [16384,16640) W1s = w0*W1   ([2][128])
//                     [16640,16768) b1s = w0*b1
//                     [16768,16896) b2s = w0*b2
#define WS_W2S 0
#define WS_W1S 16384
#define WS_B1S (16384 + 256)
#define WS_B2S (16384 + 384)

__device__ __forceinline__ float fast_sin(float x) {
    // v_sin_f32 takes revolutions; fract keeps it in [0,1) (exact, periodic).
    return __builtin_amdgcn_sinf(__builtin_amdgcn_fractf(x * 0.15915494309189535f));
}

__global__ void prep_kernel(const float* __restrict__ W1, const float* __restrict__ b1,
                            const float* __restrict__ W2, const float* __restrict__ b2,
                            float* __restrict__ ws) {
    int i = blockIdx.x * blockDim.x + threadIdx.x;
    if (i < WIDTH * WIDTH) {
        int j = i >> 7, k = i & (WIDTH - 1);
        ws[WS_W2S + i] = SIREN_W0 * W2[k * WIDTH + j];   // transpose + fold w0
    }
    if (i < 2 * WIDTH) ws[WS_W1S + i] = SIREN_W0 * W1[i];
    if (i < WIDTH)     ws[WS_B1S + i] = SIREN_W0 * b1[i];
    if (i < WIDTH)     ws[WS_B2S + i] = SIREN_W0 * b2[i];
}

__launch_bounds__(256, 2)
__global__ void ode_kernel(const float* __restrict__ t,
                           const float2* __restrict__ x0,
                           const float* __restrict__ ws,
                           const float* __restrict__ W3,
                           const float* __restrict__ b3,
                           float2* __restrict__ out) {
    const int n = blockIdx.x * blockDim.x + threadIdx.x;
    const float* __restrict__ W2s = ws + WS_W2S;
    const float* __restrict__ W1s = ws + WS_W1S;
    const float* __restrict__ b1s = ws + WS_B1S;
    const float* __restrict__ b2s = ws + WS_B2S;

    float2 y = x0[n];
    out[n] = y;                       // row 0 = x0

    const float b30 = b3[0], b31 = b3[1];

    float tprev = t[0];
    for (int step = 0; step < TSTEPS - 1; ++step) {
        const float tnext = t[step + 1];
        const float dt = tnext - tprev;
        tprev = tnext;

        float k1x = 0.f, k1y = 0.f, k2x = 0.f, k2y = 0.f, k3x = 0.f, k3y = 0.f;
        float sx = 0.f, sy = 0.f;

        // RK4 3/8-rule stage loop — kept rolled (code size), branches are
        // wave-uniform (s is an induction var) -> s_cbranch, no divergence.
        #pragma unroll 1
        for (int s = 0; s < 4; ++s) {
            float yinx, yiny;
            if (s == 0)      { yinx = y.x;                                   yiny = y.y; }
            else if (s == 1) { const float c = dt * (1.0f / 3.0f);
                               yinx = y.x + c * k1x;                          yiny = y.y + c * k1y; }
            else if (s == 2) { yinx = y.x + dt * (k2x - (1.0f/3.0f) * k1x);   yiny = y.y + dt * (k2y - (1.0f/3.0f) * k1y); }
            else             { yinx = y.x + dt * (k1x - k2x + k3x);           yiny = y.y + dt * (k1y - k2y + k3y); }

            // ---- f(yin) ----
            // Layer 1: h[j] = sin(w0*(x@W1 + b1))  (w0 pre-folded)
            float h[WIDTH];
            #pragma unroll
            for (int j = 0; j < WIDTH; ++j) {
                h[j] = fast_sin(fmaf(yinx, W1s[j], fmaf(yiny, W1s[WIDTH + j], b1s[j])));
            }

            // Layers 2+3 fused: 4 output neurons at a time, k fully unrolled.
            float fx = b30, fy = b31;
            #pragma unroll 1
            for (int j0 = 0; j0 < WIDTH; j0 += 4) {
                float a0 = b2s[j0 + 0], a1 = b2s[j0 + 1], a2 = b2s[j0 + 2], a3 = b2s[j0 + 3];
                const float* __restrict__ r0 = W2s + j0 * WIDTH;
                #pragma unroll
                for (int k = 0; k < WIDTH; ++k) {
                    const float hk = h[k];
                    a0 = fmaf(hk, r0[k],             a0);
                    a1 = fmaf(hk, r0[WIDTH + k],     a1);
                    a2 = fmaf(hk, r0[2 * WIDTH + k], a2);
                    a3 = fmaf(hk, r0[3 * WIDTH + k], a3);
                }
                a0 = fast_sin(a0); a1 = fast_sin(a1); a2 = fast_sin(a2); a3 = fast_sin(a3);
                fx = fmaf(a0, W3[(j0 + 0) * 2 + 0], fx); fy = fmaf(a0, W3[(j0 + 0) * 2 + 1], fy);
                fx = fmaf(a1, W3[(j0 + 1) * 2 + 0], fx); fy = fmaf(a1, W3[(j0 + 1) * 2 + 1], fy);
                fx = fmaf(a2, W3[(j0 + 2) * 2 + 0], fx); fy = fmaf(a2, W3[(j0 + 2) * 2 + 1], fy);
                fx = fmaf(a3, W3[(j0 + 3) * 2 + 0], fx); fy = fmaf(a3, W3[(j0 + 3) * 2 + 1], fy);
            }
            // ---- end f ----

            if (s == 0)      { k1x = fx; k1y = fy; sx = fx;          sy = fy; }
            else if (s == 1) { k2x = fx; k2y = fy; sx += 3.f * fx;   sy += 3.f * fy; }
            else if (s == 2) { k3x = fx; k3y = fy; sx += 3.f * fx;   sy += 3.f * fy; }
            else             {                     sx += fx;         sy += fy; }
        }

        const float c = dt * 0.125f;
        y.x += sx * c;
        y.y += sy * c;
        out[(size_t)(step + 1) * NPART + n] = y;
    }
}

extern "C" void kernel_launch(void* const* d_in, const int* in_sizes, int n_in,
                              void* d_out, int out_size, void* d_ws, size_t ws_size,
                              hipStream_t stream) {
    const float*  t  = (const float*)d_in[0];
    const float2* x0 = (const float2*)d_in[1];
    const float*  W1 = (const float*)d_in[2];
    const float*  b1 = (const float*)d_in[3];
    const float*  W2 = (const float*)d_in[4];
    const float*  b2 = (const float*)d_in[5];
    const float*  W3 = (const float*)d_in[6];
    const float*  b3 = (const float*)d_in[7];
    float* ws  = (float*)d_ws;
    float2* out = (float2*)d_out;

    prep_kernel<<<(WIDTH * WIDTH + 255) / 256, 256, 0, stream>>>(W1, b1, W2, b2, ws);
    ode_kernel<<<NPART / 256, 256, 0, stream>>>(t, x0, ws, W3, b3, out);
}

// Round 2
// 19909.406 us; speedup vs baseline: 3.1867x; 3.1867x over previous
//
#include <hip/hip_runtime.h>

// NeuralODE SIREN (2->128->128->2, sin, w0=44), RK4 3/8-rule, 100 steps.
// Round 2: layer-2 on MFMA bf16 with 3-term hi/lo split (residual ~2^-17,
// matching the fp32 noise floor measured in round 1: absmax 0.0156 vs thr 0.0994).
// Per wave: 64 particles (1/lane). Layer1+sin owner-lane (scalar W1 loads) ->
// per-wave LDS transpose into A-fragments (128 VGPRs) -> MFMA GEMM with
// W2-hi frags in LDS (32KB) and W2-lo frags streamed from global (L2) ->
// epilogue sin + layer3 partials in C-layout -> LDS n-reduction.
// LDS: 32KB Bhi + 4 waves x 8KB scratch = 65536 B exactly. No hot-loop
// __syncthreads: scratch is per-wave, s_waitcnt lgkmcnt(0) suffices.

#define W0F   44.0f
#define WIDTH 128
#define NPART 262144
#define TSTEPS 101

typedef short s16x8 __attribute__((ext_vector_type(8)));
typedef float f32x4 __attribute__((ext_vector_type(4)));

__device__ __forceinline__ float fast_sin(float x) {
    // v_sin_f32 takes revolutions; fract is exact (periodic).
    return __builtin_amdgcn_sinf(__builtin_amdgcn_fractf(x * 0.15915494309189535f));
}
__device__ __forceinline__ unsigned short f2bf(float x) {   // RNE f32->bf16
    __bf16 b = (__bf16)x;
    return __builtin_bit_cast(unsigned short, b);
}
__device__ __forceinline__ float bf2f(unsigned short u) {   // exact bf16->f32
    unsigned int v = ((unsigned int)u) << 16;
    return __builtin_bit_cast(float, v);
}
__device__ __forceinline__ void lds_fence() {
    // wave-internal write->read visibility; scratch is per-wave so no barrier
    __builtin_amdgcn_sched_barrier(0);
    __builtin_amdgcn_s_waitcnt(0xC07F);   // lgkmcnt(0), vmcnt/expcnt untouched
    __builtin_amdgcn_sched_barrier(0);
}

// ws layout: shorts [0,16384) = W2-hi B-frags; shorts [16384,32768) = W2-lo
// B-frags; floats [16384,16640) = w0*W1; floats [16640,16768) = w0*b1.
// Frag index i = ((nt*4+c)*64 + lane)*8 + j  <->  B[k][n], k=32c+8*(lane>>4)+j,
// n=16*nt+(lane&15)  (matches mfma_f32_16x16x32_bf16 B-operand layout).
__global__ void prep_kernel(const float* __restrict__ W1, const float* __restrict__ b1,
                            const float* __restrict__ W2, float* __restrict__ ws) {
    int i = blockIdx.x * blockDim.x + threadIdx.x;
    unsigned short* whi = (unsigned short*)ws;
    unsigned short* wlo = whi + 16384;
    if (i < 16384) {
        int j = i & 7, l = (i >> 3) & 63, c = (i >> 9) & 3, nt = (i >> 11) & 7;
        int k = 32 * c + 8 * (l >> 4) + j;
        int n = 16 * nt + (l & 15);
        float v = W0F * W2[k * WIDTH + n];
        unsigned short hi = f2bf(v);
        unsigned short lo = f2bf(v - bf2f(hi));
        whi[i] = hi;
        wlo[i] = lo;
    }
    if (i < 2 * WIDTH) ws[16384 + i] = W0F * W1[i];
    if (i < WIDTH)     ws[16384 + 256 + i] = W0F * b1[i];
}

__launch_bounds__(256, 2)
__global__ void ode_kernel(const float* __restrict__ t,
                           const float2* __restrict__ x0,
                           const float* __restrict__ ws,
                           const float* __restrict__ W3,
                           const float* __restrict__ b2,
                           const float* __restrict__ b3,
                           float2* __restrict__ out) {
    __shared__ unsigned int sB[8192];      // W2-hi fragments, 32 KB (block-shared)
    __shared__ unsigned int sS[4][2048];   // per-wave scratch, 8 KB each

    const int tid = threadIdx.x;
    const int wave = tid >> 6;
    const int lane = tid & 63;
    const int lane15 = lane & 15;
    const int kg = lane >> 4;
    const int p = blockIdx.x * 256 + tid;   // owner particle (lane l of wave w)

    // one-time: stage W2-hi fragments into LDS
    {
        const uint4* src = (const uint4*)ws;
        uint4* dst = (uint4*)sB;
        #pragma unroll
        for (int j = 0; j < 8; ++j) dst[tid + 256 * j] = src[tid + 256 * j];
    }
    __syncthreads();

    const float* W1s = ws + 16384;
    const float* b1s = ws + 16384 + 256;
    const uint4* Blo = (const uint4*)(ws + 8192);   // byte 32768: W2-lo frags

    // loop-invariant per-lane preloads (n = nt*16 + lane15)
    float b2v[8], w3xv[8], w3yv[8];
    #pragma unroll
    for (int nt = 0; nt < 8; ++nt) {
        int n = nt * 16 + lane15;
        b2v[nt] = W0F * b2[n];
        w3xv[nt] = W3[2 * n];
        w3yv[nt] = W3[2 * n + 1];
    }
    const float b30 = b3[0], b31 = b3[1];

    float2 y = x0[p];
    out[p] = y;   // row 0 = x0

    unsigned int* myS = sS[wave];

    float tprev = t[0];
    for (int step = 0; step < TSTEPS - 1; ++step) {
        const float tnext = t[step + 1];
        const float dt = tnext - tprev;
        tprev = tnext;

        float k1x=0.f,k1y=0.f,k2x=0.f,k2y=0.f,k3x=0.f,k3y=0.f,sx=0.f,sy=0.f;

        #pragma unroll 1
        for (int s = 0; s < 4; ++s) {
            float yinx, yiny;
            if (s == 0)      { yinx = y.x;                                 yiny = y.y; }
            else if (s == 1) { const float c1 = dt * (1.0f / 3.0f);
                               yinx = y.x + c1 * k1x;                       yiny = y.y + c1 * k1y; }
            else if (s == 2) { yinx = y.x + dt * (k2x - (1.0f/3.0f) * k1x); yiny = y.y + dt * (k2y - (1.0f/3.0f) * k1y); }
            else             { yinx = y.x + dt * (k1x - k2x + k3x);         yiny = y.y + dt * (k1y - k2y + k3y); }

            // ---- f(yin) ----
            // Phase 1: layer1+sin owner-lane, split to bf16 hi/lo, transpose
            // per 32-k chunk through per-wave scratch into A-fragments.
            uint4 Ahi[4][4], Alo[4][4];
            #pragma unroll
            for (int c = 0; c < 4; ++c) {
                #pragma unroll
                for (int j8 = 0; j8 < 4; ++j8) {
                    unsigned int hp[4], lp[4];
                    #pragma unroll
                    for (int e2 = 0; e2 < 4; ++e2) {
                        int k0 = 32 * c + 8 * j8 + 2 * e2;
                        float v0 = fast_sin(fmaf(yinx, W1s[k0],   fmaf(yiny, W1s[WIDTH + k0],   b1s[k0])));
                        float v1 = fast_sin(fmaf(yinx, W1s[k0+1], fmaf(yiny, W1s[WIDTH + k0+1], b1s[k0+1])));
                        unsigned short h0 = f2bf(v0), h1 = f2bf(v1);
                        unsigned short l0 = f2bf(v0 - bf2f(h0)), l1 = f2bf(v1 - bf2f(h1));
                        hp[e2] = (unsigned int)h0 | ((unsigned int)h1 << 16);
                        lp[e2] = (unsigned int)l0 | ((unsigned int)l1 << 16);
                    }
                    uint4 H = make_uint4(hp[0], hp[1], hp[2], hp[3]);
                    uint4 L = make_uint4(lp[0], lp[1], lp[2], lp[3]);
                    uint4* rowp = (uint4*)(myS + lane * 32);   // row 'lane', 128B
                    rowp[(j8 + lane) & 7]     = H;             // bank-swizzled quads
                    rowp[(4 + j8 + lane) & 7] = L;
                }
                lds_fence();
                #pragma unroll
                for (int mt = 0; mt < 4; ++mt) {
                    int row = mt * 16 + lane15;
                    const uint4* rp = (const uint4*)(myS + row * 32);
                    Ahi[mt][c] = rp[(kg + row) & 7];
                    Alo[mt][c] = rp[(4 + kg + row) & 7];
                }
                // next c overwrites scratch: per-wave LDS ops are in-order -> safe
            }

            // Phase 2: GEMM (3-term split) + epilogue sin + layer3 partials
            float fxa[16], fya[16];
            #pragma unroll
            for (int i = 0; i < 16; ++i) { fxa[i] = 0.f; fya[i] = 0.f; }

            #pragma unroll
            for (int nt = 0; nt < 8; ++nt) {
                f32x4 acc[4];
                #pragma unroll
                for (int mt = 0; mt < 4; ++mt) acc[mt] = (f32x4){0.f, 0.f, 0.f, 0.f};
                #pragma unroll
                for (int c = 0; c < 4; ++c) {
                    uint4 bhU = *(const uint4*)&sB[(nt * 4 + c) * 256 + lane * 4];
                    uint4 blU = Blo[(nt * 4 + c) * 64 + lane];
                    s16x8 bh = __builtin_bit_cast(s16x8, bhU);
                    s16x8 bl = __builtin_bit_cast(s16x8, blU);
                    #pragma unroll
                    for (int mt = 0; mt < 4; ++mt) {
                        s16x8 ah = __builtin_bit_cast(s16x8, Ahi[mt][c]);
                        s16x8 al = __builtin_bit_cast(s16x8, Alo[mt][c]);
                        acc[mt] = __builtin_amdgcn_mfma_f32_16x16x32_bf16(ah, bh, acc[mt], 0, 0, 0);
                        acc[mt] = __builtin_amdgcn_mfma_f32_16x16x32_bf16(al, bh, acc[mt], 0, 0, 0);
                        acc[mt] = __builtin_amdgcn_mfma_f32_16x16x32_bf16(ah, bl, acc[mt], 0, 0, 0);
                    }
                }
                #pragma unroll
                for (int mt = 0; mt < 4; ++mt) {
                    #pragma unroll
                    for (int r = 0; r < 4; ++r) {
                        float z = acc[mt][r] + b2v[nt];
                        float sn = fast_sin(z);
                        fxa[mt * 4 + r] = fmaf(sn, w3xv[nt], fxa[mt * 4 + r]);
                        fya[mt * 4 + r] = fmaf(sn, w3yv[nt], fya[mt * 4 + r]);
                    }
                }
            }

            // Phase 3: reduce over the 16 n-lanes (2 rounds through scratch).
            // C-layout: value (mt,r) in lane l is row m=4*kg+r of tile mt,
            // col n = lane15; particle q = mt*16 + 4*kg + r.
            float fx = b30, fy = b31;
            float2* f2S = (float2*)myS;
            #pragma unroll
            for (int g = 0; g < 2; ++g) {
                #pragma unroll
                for (int m2 = 0; m2 < 2; ++m2) {
                    int mt = g * 2 + m2;
                    #pragma unroll
                    for (int r = 0; r < 4; ++r) {
                        int qr = m2 * 16 + 4 * kg + r;           // q - 32g
                        int pos = (lane15 + 2 * (qr & 7)) & 15;  // rotated (pairwise)
                        f2S[qr * 16 + pos] = make_float2(fxa[mt * 4 + r], fya[mt * 4 + r]);
                    }
                }
                lds_fence();
                if ((lane >> 5) == g) {
                    int qr = lane & 31;
                    const float4* rp4 = ((const float4*)myS) + qr * 8;
                    float sxx = 0.f, syy = 0.f;
                    #pragma unroll
                    for (int j = 0; j < 8; ++j) {
                        float4 u = rp4[(j + (qr & 7)) & 7];      // order-free sum
                        sxx += u.x + u.z;
                        syy += u.y + u.w;
                    }
                    fx += sxx;
                    fy += syy;
                }
                // round 1 writes after round 0 reads: per-wave in-order -> safe
            }
            // ---- end f ----

            if (s == 0)      { k1x = fx; k1y = fy; sx = fx;        sy = fy; }
            else if (s == 1) { k2x = fx; k2y = fy; sx += 3.f * fx; sy += 3.f * fy; }
            else if (s == 2) { k3x = fx; k3y = fy; sx += 3.f * fx; sy += 3.f * fy; }
            else             {                     sx += fx;       sy += fy; }
        }

        const float cc = dt * 0.125f;
        y.x += sx * cc;
        y.y += sy * cc;
        out[(size_t)(step + 1) * NPART + p] = y;
    }
}

extern "C" void kernel_launch(void* const* d_in, const int* in_sizes, int n_in,
                              void* d_out, int out_size, void* d_ws, size_t ws_size,
                              hipStream_t stream) {
    const float*  t  = (const float*)d_in[0];
    const float2* x0 = (const float2*)d_in[1];
    const float*  W1 = (const float*)d_in[2];
    const float*  b1 = (const float*)d_in[3];
    const float*  W2 = (const float*)d_in[4];
    const float*  b2 = (const float*)d_in[5];
    const float*  W3 = (const float*)d_in[6];
    const float*  b3 = (const float*)d_in[7];
    float* ws = (float*)d_ws;
    float2* out = (float2*)d_out;

    prep_kernel<<<64, 256, 0, stream>>>(W1, b1, W2, ws);
    ode_kernel<<<NPART / 256, 256, 0, stream>>>(t, x0, ws, W3, b2, b3, out);
}